// Round 1
// baseline (540.507 us; speedup 1.0000x reference)
//
#include <hip/hip_runtime.h>
#include <stdint.h>

#define NN 128
#define BB 4096
#define HH 32

// Pre-pass: bit-pack A transposed. bit d of word (b,node) = (A[b][d][node] != 0).
// Coalesced reads (lanes along `node`), 16B/thread coalesced writes.
__global__ __launch_bounds__(256) void pack_bits(const float* __restrict__ A,
                                                 ulonglong2* __restrict__ bitsT) {
    int tid = blockIdx.x * 256 + threadIdx.x;
    int b = tid >> 7;
    int node = tid & 127;
    const float* Ab = A + (size_t)b * NN * NN + node;
    unsigned long long w0 = 0, w1 = 0;
#pragma unroll 8
    for (int d = 0; d < 64; ++d) {
        float v = __builtin_nontemporal_load(&Ab[d * NN]);
        if (v != 0.f) w0 |= 1ull << d;
    }
#pragma unroll 8
    for (int d = 0; d < 64; ++d) {
        float v = __builtin_nontemporal_load(&Ab[(d + 64) * NN]);
        if (v != 0.f) w1 |= 1ull << d;
    }
    ulonglong2 r; r.x = w0; r.y = w1;
    bitsT[tid] = r;
}

// One wave (64 lanes) per batch element. outputs state: out0 (d=lane), out1 (d=lane+64).
// Per step: ballot-compact nonzero (value, d) pairs into LDS, sparse-gather W1 rows.
__global__ __launch_bounds__(64) void cond_mlp(
    const float* __restrict__ x, const float* __restrict__ u,
    const float* __restrict__ W1, const float* __restrict__ b1,
    const float* __restrict__ W2, const float* __restrict__ b2,
    const int* __restrict__ order, const int* __restrict__ do_idxs,
    const ulonglong2* __restrict__ bitsT, float* __restrict__ out)
{
    const int b = blockIdx.x;
    const int lane = threadIdx.x;
    const int j = lane & 31;       // hidden index
    const int half = lane >> 5;    // which k-stream this lane serves

    __shared__ float2 ent[132];    // compacted (value, d-as-bits) list

    const float ub = u[b];
    const int dob = do_idxs[b];
    float out0 = (dob == lane) ? ub : 0.f;
    float out1 = (dob == lane + 64) ? ub : 0.f;

    const int* ord = order + b * NN;
    const ulonglong2* bb = bitsT + (size_t)b * NN;

    int node = ord[0];
    ulonglong2 bits = bb[node];

    for (int t = 0; t < NN; ++t) {
        // ---- prefetch next step's uniform data (overlaps with this step) ----
        const int node_n = (t < NN - 1) ? ord[t + 1] : 0;
        const ulonglong2 bits_n = bb[node_n];

        const float* Wn = W1 + (size_t)node * (NN + 1) * HH;
        // issue epilogue loads early (consumed after the gather loop)
        const float w2v = W2[node * HH + j];
        const float b1v = b1[node * HH + j];
        const float xv  = x[b * NN + node];
        const float b2v = b2[node];

        // ---- wave-uniform sparse compaction ----
        unsigned long long bal0 = __ballot(out0 != 0.f) & bits.x;
        unsigned long long bal1 = __ballot(out1 != 0.f) & bits.y;
        const int c0 = __popcll(bal0);
        const int cnt = c0 + __popcll(bal1);
        const unsigned long long below = (1ull << lane) - 1;
        if (bal0 & (1ull << lane)) {
            int p = __popcll(bal0 & below);
            ent[p] = make_float2(out0, __int_as_float(lane));
        }
        if (bal1 & (1ull << lane)) {
            int p = c0 + __popcll(bal1 & below);
            ent[p] = make_float2(out1, __int_as_float(lane + 64));
        }
        const int cnt4 = (cnt + 3) & ~3;
        if (lane < cnt4 - cnt) ent[cnt + lane] = make_float2(0.f, __int_as_float(0));
        __syncthreads();

        // ---- sparse gather: half 0 takes k, k+2; half 1 takes k+1, k+3 ----
        float acc0 = 0.f, acc1 = 0.f;
        for (int k = 0; k < cnt4; k += 4) {
            float2 eA = ent[k + half];
            float2 eB = ent[k + 2 + half];
            int dA = __float_as_int(eA.y);
            int dB = __float_as_int(eB.y);
            acc0 += eA.x * Wn[dA * HH + j];
            acc1 += eB.x * Wn[dB * HH + j];
        }
        __syncthreads();   // ent fully consumed before next step's writes

        float acc = acc0 + acc1;
        acc += __shfl_xor(acc, 32);            // merge the two k-streams
        acc += xv * Wn[NN * HH + j];           // the x input row (row 128)
        acc += b1v;
        const float hv = (acc > 0.f) ? acc : 0.01f * acc;   // leaky_relu

        float p = hv * w2v;                    // H -> 1 reduction
        p += __shfl_xor(p, 16);
        p += __shfl_xor(p, 8);
        p += __shfl_xor(p, 4);
        p += __shfl_xor(p, 2);
        p += __shfl_xor(p, 1);
        const float outv = p + b2v;

        // ---- state update (skip if this is the do-intervention node) ----
        if (dob != node) {
            if (lane == (node & 63)) {
                if (node < 64) out0 = outv; else out1 = outv;
            }
        }
        node = node_n;
        bits = bits_n;
    }

    out[b * NN + lane] = out0;
    out[b * NN + 64 + lane] = out1;
}

extern "C" void kernel_launch(void* const* d_in, const int* in_sizes, int n_in,
                              void* d_out, int out_size, void* d_ws, size_t ws_size,
                              hipStream_t stream) {
    const float* x   = (const float*)d_in[0];
    const float* A   = (const float*)d_in[1];
    const float* u   = (const float*)d_in[2];
    const float* W1  = (const float*)d_in[3];
    const float* b1  = (const float*)d_in[4];
    const float* W2  = (const float*)d_in[5];
    const float* b2  = (const float*)d_in[6];
    const int* order = (const int*)d_in[7];
    const int* dox   = (const int*)d_in[8];

    ulonglong2* bitsT = (ulonglong2*)d_ws;  // needs 4096*128*16 B = 8 MB

    pack_bits<<<(BB * NN) / 256, 256, 0, stream>>>(A, bitsT);
    cond_mlp<<<BB, 64, 0, stream>>>(x, u, W1, b1, W2, b2, order, dox,
                                    bitsT, (float*)d_out);
}